// Round 13
// baseline (1261.580 us; speedup 1.0000x reference)
//
#include <hip/hip_runtime.h>

typedef _Float16 half8 __attribute__((ext_vector_type(8)));
typedef float f32x4 __attribute__((ext_vector_type(4)));

#define TT 48
#define BT 16
#define NSEQ 16384
#define NGRP (NSEQ / BT)
#define NTHR 512
#define MAXGRID 512
#define H0_SLICE (TT * BT * 136)   // f16 elems per block ws slice (208896 B)

// h0w layout: [t][d][b][j]  (stride per t = 2176 f16)
struct __align__(16) Smem {
  float gates[272 * 17];      // 18496 B  gate pre-activations [gate][b(+pad)]
  _Float16 A[16 * 232];       //  7424 B  A panel (L0 view: [16][136])
  float yscr[16 * 5 * 32];    // 10240 B  FC partial scratch
  _Float16 bx[7 * 64 * 8];    //  7168 B  LDS B-fragments for tile 16 (gates 256-271)
};                            // 43328 B static LDS

__device__ __forceinline__ float fast_rcp(float v) { return __builtin_amdgcn_rcpf(v); }
__device__ __forceinline__ float sigm(float v)  { return fast_rcp(1.f + __expf(-v)); }
__device__ __forceinline__ float tanh_s(float v){ return 1.f - 2.f * fast_rcp(1.f + __expf(2.f * v)); }

// One (layer, dir) recurrence, all 8 waves. Wave w owns reg tiles {2w, 2w+1};
// tile 16 is computed by wave 0 from LDS-resident B fragments (bx).
template <int LAYER>
__device__ __forceinline__ void pass_lstm(Smem& s, const int d,
    const float* __restrict__ Wih, const float* __restrict__ Whh,
    const float* __restrict__ bih, const float* __restrict__ bhh,
    const float* __restrict__ xg,  const float* __restrict__ fcw,
    _Float16* __restrict__ h0w, float (&yk)[5])
{
  constexpr int AW    = LAYER ? 232 : 136;  // A row stride (f16)
  constexpr int KS    = LAYER ? 7 : 4;      // K chunks of 32 (224 / 128)
  constexpr int INW   = LAYER ? 136 : 34;   // non-recurrent width
  constexpr int BIASC = INW + 68;           // bias-one column (204 / 102)
  constexpr int HOFF  = LAYER ? 136 : 34;   // h slot base in A row

  const int tid = threadIdx.x;
  const int ln = tid & 63, wid = tid >> 6;
  const int lr = ln & 15, lq = ln >> 4;
  const int b_ = tid >> 5, m_ = tid & 31;   // elementwise ownership

  // ---- reg B fragments: 2 tiles per wave (2*KS*4 <= 56 VGPR) ----
  half8 Bf[2][KS];
  #pragma unroll
  for (int i = 0; i < 2; ++i) {
    const int g = (wid * 2 + i) * 16 + lr;
    #pragma unroll
    for (int kk = 0; kk < KS; ++kk) {
      half8 v;
      #pragma unroll
      for (int j = 0; j < 8; ++j) {
        const int k = kk * 32 + lq * 8 + j;
        float wv = 0.f;
        if (k < INW) wv = Wih[g * INW + k];
        else if (k < BIASC) wv = Whh[g * 68 + (k - INW)];
        else if (k == BIASC) wv = bih[g] + bhh[g];
        v[j] = (_Float16)wv;
      }
      Bf[i][kk] = v;
    }
  }
  // ---- LDS B fragments for tile 16: slot (kk, lane) = that lane's half8 ----
  if (tid < KS * 64) {
    const int kk = tid >> 6, l2 = tid & 63;
    const int g = 256 + (l2 & 15);
    half8 v;
    #pragma unroll
    for (int j = 0; j < 8; ++j) {
      const int k = kk * 32 + (l2 >> 4) * 8 + j;
      float wv = 0.f;
      if (k < INW) wv = Wih[g * INW + k];
      else if (k < BIASC) wv = Whh[g * 68 + (k - INW)];
      else if (k == BIASC) wv = bih[g] + bhh[g];
      v[j] = (_Float16)wv;
    }
    *(half8*)&s.bx[tid * 8] = v;
  }
  float cst[3] = {0.f, 0.f, 0.f};

  // ---- staging offsets (t-independent); 544 tasks = 512 + 32 extras ----
  int sgo, sao, sgo2, sao2;
  if constexpr (LAYER == 0) {
    const int b = tid / 34, i = tid % 34;
    sgo = b * (TT * 34) + i;  sao = b * 136 + i;
    const int u2 = 512 + tid, b2 = u2 / 34, i2 = u2 % 34;
    sgo2 = b2 * (TT * 34) + i2;  sao2 = b2 * 136 + i2;
  } else {
    const int dd = tid / 272, r = tid % 272, b = r / 17, c = r % 17;
    sgo = dd * 1088 + b * 68 + c * 4;  sao = b * 232 + dd * 68 + c * 4;
    const int u2 = 512 + tid, dd2 = u2 / 272, r2 = u2 % 272, b2 = r2 / 17, c2 = r2 % 17;
    sgo2 = dd2 * 1088 + b2 * 68 + c2 * 4;  sao2 = b2 * 232 + dd2 * 68 + c2 * 4;
  }

  // ---- prologue: zero A, bias col, stage step 0 ----
  if (tid < AW * 2) ((uint4*)s.A)[tid] = (uint4){0, 0, 0, 0};
  __syncthreads();
  if (tid < 16) s.A[tid * AW + BIASC] = (_Float16)1.f;
  const int t0 = d ? (TT - 1) : 0;
  if constexpr (LAYER == 0) {
    s.A[sao] = (_Float16)xg[sgo + t0 * 34];
    if (tid < 32) s.A[sao2] = (_Float16)xg[sgo2 + t0 * 34];
  } else {
    *(uint2*)&s.A[sao] = *(const uint2*)&h0w[sgo + t0 * 2176];
    if (tid < 32) *(uint2*)&s.A[sao2] = *(const uint2*)&h0w[sgo2 + t0 * 2176];
  }
  __syncthreads();

  #pragma unroll 1
  for (int st = 0; st < TT; ++st) {
    const int t  = d ? (TT - 1 - st) : st;
    const int tn = d ? (t - 1) : (t + 1);

    // ---- prefetch next step's staging into registers ----
    float xp0 = 0.f, xp1 = 0.f;
    uint2 hp0 = {0, 0}, hp1 = {0, 0};
    if (st < TT - 1) {
      if constexpr (LAYER == 0) {
        xp0 = xg[sgo + tn * 34];
        if (tid < 32) xp1 = xg[sgo2 + tn * 34];
      } else {
        hp0 = *(const uint2*)&h0w[sgo + tn * 2176];
        if (tid < 32) hp1 = *(const uint2*)&h0w[sgo2 + tn * 2176];
      }
    }

    // ---- MFMA: gates(16x272) = A(16xK) . B(Kx272) ----
    f32x4 acc0 = {0.f,0.f,0.f,0.f}, acc1 = {0.f,0.f,0.f,0.f}, acc2 = {0.f,0.f,0.f,0.f};
    #pragma unroll
    for (int kk = 0; kk < KS; ++kk) {
      const half8 a = *(const half8*)&s.A[lr * AW + kk * 32 + lq * 8];
      acc0 = __builtin_amdgcn_mfma_f32_16x16x32_f16(a, Bf[0][kk], acc0, 0, 0, 0);
      acc1 = __builtin_amdgcn_mfma_f32_16x16x32_f16(a, Bf[1][kk], acc1, 0, 0, 0);
      if (wid == 0) {
        const half8 bb = *(const half8*)&s.bx[(kk * 64 + ln) * 8];
        acc2 = __builtin_amdgcn_mfma_f32_16x16x32_f16(a, bb, acc2, 0, 0, 0);
      }
    }
    // C/D: col = lr (gate within tile), row = lq*4+r (batch)
    {
      const int g0 = (wid * 2) * 16 + lr;
      #pragma unroll
      for (int r = 0; r < 4; ++r) {
        s.gates[g0 * 17 + lq * 4 + r] = acc0[r];
        s.gates[(g0 + 16) * 17 + lq * 4 + r] = acc1[r];
      }
      if (wid == 0) {
        #pragma unroll
        for (int r = 0; r < 4; ++r)
          s.gates[(256 + lr) * 17 + lq * 4 + r] = acc2[r];
      }
    }
    __syncthreads();

    // ---- elementwise: thread owns (b_, j = m_ / m_+32 / m_+64 if m_<4) ----
    #pragma unroll
    for (int q = 0; q < 3; ++q) {
      if (q < 2 || m_ < 4) {
        const int j = m_ + 32 * q;
        const float gi = s.gates[j * 17 + b_];
        const float gf = s.gates[(68 + j) * 17 + b_];
        const float gg = s.gates[(136 + j) * 17 + b_];
        const float go = s.gates[(204 + j) * 17 + b_];
        const float ii = sigm(gi), ff = sigm(gf), g2 = tanh_s(gg), oo = sigm(go);
        const float cc = ff * cst[q] + ii * g2;
        cst[q] = cc;
        const float h = oo * tanh_s(cc);
        const _Float16 h16 = (_Float16)h;
        s.A[b_ * AW + HOFF + j] = h16;
        if constexpr (LAYER == 0) {
          h0w[t * 2176 + d * 1088 + b_ * 68 + j] = h16;
        } else {
          const int fo = t * 136 + d * 68 + j;
          #pragma unroll
          for (int k = 0; k < 5; ++k) yk[k] += h * fcw[k * 6528 + fo];
        }
      }
    }
    // ---- staging writes for next step ----
    if (st < TT - 1) {
      if constexpr (LAYER == 0) {
        s.A[sao] = (_Float16)xp0;
        if (tid < 32) s.A[sao2] = (_Float16)xp1;
      } else {
        *(uint2*)&s.A[sao] = hp0;
        if (tid < 32) *(uint2*)&s.A[sao2] = hp1;
      }
    }
    __syncthreads();
  }
}

__global__ __attribute__((amdgpu_flat_work_group_size(NTHR, NTHR)))
void lstm_fc_kernel(
    const float* __restrict__ x,
    const float* __restrict__ Wih0f, const float* __restrict__ Whh0f,
    const float* __restrict__ bih0f, const float* __restrict__ bhh0f,
    const float* __restrict__ Wih0b, const float* __restrict__ Whh0b,
    const float* __restrict__ bih0b, const float* __restrict__ bhh0b,
    const float* __restrict__ Wih1f, const float* __restrict__ Whh1f,
    const float* __restrict__ bih1f, const float* __restrict__ bhh1f,
    const float* __restrict__ Wih1b, const float* __restrict__ Whh1b,
    const float* __restrict__ bih1b, const float* __restrict__ bhh1b,
    const float* __restrict__ fcw, const float* __restrict__ fcb,
    float* __restrict__ out, _Float16* __restrict__ ws)
{
  __shared__ Smem s;
  const int tid = threadIdx.x;
  _Float16* h0w = ws + (size_t)blockIdx.x * H0_SLICE;

  for (int grp = blockIdx.x; grp < NGRP; grp += gridDim.x) {
    const float* xg = x + (size_t)grp * (BT * TT * 34);
    float yk[5] = {0.f, 0.f, 0.f, 0.f, 0.f};

    pass_lstm<0>(s, 0, Wih0f, Whh0f, bih0f, bhh0f, xg, nullptr, h0w, yk);
    pass_lstm<0>(s, 1, Wih0b, Whh0b, bih0b, bhh0b, xg, nullptr, h0w, yk);
    pass_lstm<1>(s, 0, Wih1f, Whh1f, bih1f, bhh1f, nullptr, fcw, h0w, yk);
    pass_lstm<1>(s, 1, Wih1b, Whh1b, bih1b, bhh1b, nullptr, fcw, h0w, yk);

    // ---- FC epilogue ----
    {
      const int b_ = tid >> 5, m_ = tid & 31;
      #pragma unroll
      for (int k = 0; k < 5; ++k) s.yscr[(b_ * 5 + k) * 32 + m_] = yk[k];
    }
    __syncthreads();
    if (tid < 80) {
      const int b = tid / 5, k = tid - (tid / 5) * 5;
      float v = fcb[k];
      #pragma unroll 8
      for (int m = 0; m < 32; ++m) v += s.yscr[(b * 5 + k) * 32 + m];
      out[(size_t)(grp * BT + b) * 5 + k] = v;
    }
    __syncthreads();
  }
}

extern "C" void kernel_launch(void* const* d_in, const int* in_sizes, int n_in,
                              void* d_out, int out_size, void* d_ws, size_t ws_size,
                              hipStream_t stream) {
  (void)in_sizes; (void)n_in; (void)out_size;
  static_assert(sizeof(Smem) <= 60 * 1024, "LDS budget for 2 blocks/CU");

  const float* x     = (const float*)d_in[0];
  const float* Wih0f = (const float*)d_in[1];
  const float* Whh0f = (const float*)d_in[2];
  const float* bih0f = (const float*)d_in[3];
  const float* bhh0f = (const float*)d_in[4];
  const float* Wih0b = (const float*)d_in[5];
  const float* Whh0b = (const float*)d_in[6];
  const float* bih0b = (const float*)d_in[7];
  const float* bhh0b = (const float*)d_in[8];
  const float* Wih1f = (const float*)d_in[9];
  const float* Whh1f = (const float*)d_in[10];
  const float* bih1f = (const float*)d_in[11];
  const float* bhh1f = (const float*)d_in[12];
  const float* Wih1b = (const float*)d_in[13];
  const float* Whh1b = (const float*)d_in[14];
  const float* bih1b = (const float*)d_in[15];
  const float* bhh1b = (const float*)d_in[16];
  const float* fcw   = (const float*)d_in[17];
  const float* fcb   = (const float*)d_in[18];
  float* out = (float*)d_out;

  int slices = (int)(ws_size / (size_t)(H0_SLICE * 2));
  int grid = slices < 1 ? 1 : (slices > MAXGRID ? MAXGRID : slices);

  lstm_fc_kernel<<<dim3(grid), dim3(NTHR), 0, stream>>>(x,
      Wih0f, Whh0f, bih0f, bhh0f, Wih0b, Whh0b, bih0b, bhh0b,
      Wih1f, Whh1f, bih1f, bhh1f, Wih1b, Whh1b, bih1b, bhh1b,
      fcw, fcb, out, (_Float16*)d_ws);
}

// Round 14
// 1222.738 us; speedup vs baseline: 1.0318x; 1.0318x over previous
//
#include <hip/hip_runtime.h>

typedef _Float16 half8 __attribute__((ext_vector_type(8)));
typedef float f32x4 __attribute__((ext_vector_type(4)));

#define TT 48
#define BT 32
#define NSEQ 16384
#define NGRP (NSEQ / BT)           // 512 groups
#define NTHR 512
#define MAXGRID 512
#define H0_SLICE (TT * BT * 136)   // f16 elems per block ws slice (417792 B)

// h0w layout: [t][d][b][j], stride per t = 4352 f16
struct __align__(16) Smem {
  union {
    struct {
      float gates[272 * 33];    // 35904 B  [gate][batch(+pad)]
      _Float16 A[32 * 232];     // 14848 B  A panel (L0 view: [32][136])
    } m;
    float ysc[2176 * 5];        // 43520 B  FC scratch (overlays gates+A after L1)
  } u;
  _Float16 bx[7 * 64 * 8];      //  7168 B  LDS B-fragments for tile 16
};                              // 57920 B static LDS

__device__ __forceinline__ float fast_rcp(float v) { return __builtin_amdgcn_rcpf(v); }
__device__ __forceinline__ float sigm(float v)  { return fast_rcp(1.f + __expf(-v)); }
__device__ __forceinline__ float tanh_s(float v){ return 1.f - 2.f * fast_rcp(1.f + __expf(2.f * v)); }

// One (layer, dir) recurrence over 32 sequences, all 8 waves.
// Wave w owns reg B-tiles {2w, 2w+1}; tile 16 via LDS bx (wave 0). M=32 = lo/hi A-tiles.
template <int LAYER>
__device__ __forceinline__ void pass_lstm(Smem& s, const int d,
    const float* __restrict__ Wih, const float* __restrict__ Whh,
    const float* __restrict__ bih, const float* __restrict__ bhh,
    const float* __restrict__ xg,  const float* __restrict__ fcw,
    _Float16* __restrict__ h0w, float (&yk)[5][5])
{
  constexpr int AW    = LAYER ? 232 : 136;  // A row stride (f16)
  constexpr int KS    = LAYER ? 7 : 4;      // K chunks of 32 (224 / 128)
  constexpr int INW   = LAYER ? 136 : 34;   // non-recurrent width
  constexpr int BIASC = INW + 68;           // bias-one column (204 / 102)
  constexpr int HOFF  = LAYER ? 136 : 34;   // h slot base in A row

  const int tid = threadIdx.x;
  const int ln = tid & 63, wid = tid >> 6;
  const int lr = ln & 15, lq = ln >> 4;

  float* gates = s.u.m.gates;
  _Float16* A  = s.u.m.A;

  // ---- reg B fragments: 2 tiles per wave ----
  half8 Bf[2][KS];
  #pragma unroll
  for (int i = 0; i < 2; ++i) {
    const int g = (wid * 2 + i) * 16 + lr;
    #pragma unroll
    for (int kk = 0; kk < KS; ++kk) {
      half8 v;
      #pragma unroll
      for (int j = 0; j < 8; ++j) {
        const int k = kk * 32 + lq * 8 + j;
        float wv = 0.f;
        if (k < INW) wv = Wih[g * INW + k];
        else if (k < BIASC) wv = Whh[g * 68 + (k - INW)];
        else if (k == BIASC) wv = bih[g] + bhh[g];
        v[j] = (_Float16)wv;
      }
      Bf[i][kk] = v;
    }
  }
  // ---- LDS B fragments for tile 16 ----
  if (tid < KS * 64) {
    const int kk = tid >> 6, l2 = tid & 63;
    const int g = 256 + (l2 & 15);
    half8 v;
    #pragma unroll
    for (int j = 0; j < 8; ++j) {
      const int k = kk * 32 + (l2 >> 4) * 8 + j;
      float wv = 0.f;
      if (k < INW) wv = Wih[g * INW + k];
      else if (k < BIASC) wv = Whh[g * 68 + (k - INW)];
      else if (k == BIASC) wv = bih[g] + bhh[g];
      v[j] = (_Float16)wv;
    }
    *(half8*)&s.bx[tid * 8] = v;
  }

  // ---- elementwise pairs: 2176 = 32b x 68j tasks; 4/thread + 128 extras ----
  int pb_[5], pj_[5];
  float cst[5];
  #pragma unroll
  for (int q = 0; q < 5; ++q) {
    const int p = (q < 4) ? (q * 512 + tid) : (2048 + (tid & 127));
    pb_[q] = p / 68; pj_[q] = p - (p / 68) * 68;
    cst[q] = 0.f;
  }

  // ---- staging offsets (t-independent); 1088 tasks = 2*512 + 64 extras ----
  int sgo0, sao0, sgo1, sao1, sgo2, sao2;
  if constexpr (LAYER == 0) {
    { const int b = tid / 34, i = tid % 34;
      sgo0 = b * (TT * 34) + i;  sao0 = b * 136 + i; }
    { const int t1 = tid + 512, b = t1 / 34, i = t1 % 34;
      sgo1 = b * (TT * 34) + i;  sao1 = b * 136 + i; }
    { const int t2 = (tid < 64) ? (tid + 1024) : 1024, b = t2 / 34, i = t2 % 34;
      sgo2 = b * (TT * 34) + i;  sao2 = b * 136 + i; }
  } else {
    { const int dd = tid / 544, r = tid % 544, b = r / 17, c = r % 17;
      sgo0 = dd * 2176 + b * 68 + c * 4;  sao0 = b * 232 + dd * 68 + c * 4; }
    { const int t1 = tid + 512, dd = t1 / 544, r = t1 % 544, b = r / 17, c = r % 17;
      sgo1 = dd * 2176 + b * 68 + c * 4;  sao1 = b * 232 + dd * 68 + c * 4; }
    { const int t2 = (tid < 64) ? (tid + 1024) : 1024, dd = t2 / 544, r = t2 % 544,
        b = r / 17, c = r % 17;
      sgo2 = dd * 2176 + b * 68 + c * 4;  sao2 = b * 232 + dd * 68 + c * 4; }
  }

  // ---- prologue: zero A (928 uint4), bias col, stage step 0 ----
  {
    const uint4 zz = {0, 0, 0, 0};
    ((uint4*)A)[tid] = zz;
    if (tid < 416) ((uint4*)A)[512 + tid] = zz;
  }
  __syncthreads();
  if (tid < 32) A[tid * AW + BIASC] = (_Float16)1.f;
  const int t0 = d ? (TT - 1) : 0;
  if constexpr (LAYER == 0) {
    A[sao0] = (_Float16)xg[sgo0 + t0 * 34];
    A[sao1] = (_Float16)xg[sgo1 + t0 * 34];
    if (tid < 64) A[sao2] = (_Float16)xg[sgo2 + t0 * 34];
  } else {
    *(uint2*)&A[sao0] = *(const uint2*)&h0w[sgo0 + t0 * 4352];
    *(uint2*)&A[sao1] = *(const uint2*)&h0w[sgo1 + t0 * 4352];
    if (tid < 64) *(uint2*)&A[sao2] = *(const uint2*)&h0w[sgo2 + t0 * 4352];
  }
  __syncthreads();

  #pragma unroll 1
  for (int st = 0; st < TT; ++st) {
    const int t  = d ? (TT - 1 - st) : st;
    const int tn = d ? (t - 1) : (t + 1);

    // ---- prefetch next step's staging into registers ----
    float xp0 = 0.f, xp1 = 0.f, xp2 = 0.f;
    uint2 hp0 = {0, 0}, hp1 = {0, 0}, hp2 = {0, 0};
    if (st < TT - 1) {
      if constexpr (LAYER == 0) {
        xp0 = xg[sgo0 + tn * 34];
        xp1 = xg[sgo1 + tn * 34];
        if (tid < 64) xp2 = xg[sgo2 + tn * 34];
      } else {
        hp0 = *(const uint2*)&h0w[sgo0 + tn * 4352];
        hp1 = *(const uint2*)&h0w[sgo1 + tn * 4352];
        if (tid < 64) hp2 = *(const uint2*)&h0w[sgo2 + tn * 4352];
      }
    }

    // ---- MFMA: gates(32x272) = A(32xK) . B(Kx272); lo/hi 16-row tiles ----
    f32x4 aL0 = {0.f,0.f,0.f,0.f}, aH0 = {0.f,0.f,0.f,0.f};
    f32x4 aL1 = {0.f,0.f,0.f,0.f}, aH1 = {0.f,0.f,0.f,0.f};
    f32x4 aL2 = {0.f,0.f,0.f,0.f}, aH2 = {0.f,0.f,0.f,0.f};
    #pragma unroll
    for (int kk = 0; kk < KS; ++kk) {
      const half8 alo = *(const half8*)&A[lr * AW + kk * 32 + lq * 8];
      const half8 ahi = *(const half8*)&A[(lr + 16) * AW + kk * 32 + lq * 8];
      aL0 = __builtin_amdgcn_mfma_f32_16x16x32_f16(alo, Bf[0][kk], aL0, 0, 0, 0);
      aH0 = __builtin_amdgcn_mfma_f32_16x16x32_f16(ahi, Bf[0][kk], aH0, 0, 0, 0);
      aL1 = __builtin_amdgcn_mfma_f32_16x16x32_f16(alo, Bf[1][kk], aL1, 0, 0, 0);
      aH1 = __builtin_amdgcn_mfma_f32_16x16x32_f16(ahi, Bf[1][kk], aH1, 0, 0, 0);
      if (wid == 0) {
        const half8 bb = *(const half8*)&s.bx[(kk * 64 + ln) * 8];
        aL2 = __builtin_amdgcn_mfma_f32_16x16x32_f16(alo, bb, aL2, 0, 0, 0);
        aH2 = __builtin_amdgcn_mfma_f32_16x16x32_f16(ahi, bb, aH2, 0, 0, 0);
      }
    }
    // C/D: col = lr (gate within tile), row = lq*4+r (batch; +16 for hi tile)
    {
      const int g0 = (wid * 2) * 16 + lr;
      #pragma unroll
      for (int r = 0; r < 4; ++r) {
        gates[g0 * 33 + lq * 4 + r]              = aL0[r];
        gates[g0 * 33 + 16 + lq * 4 + r]         = aH0[r];
        gates[(g0 + 16) * 33 + lq * 4 + r]       = aL1[r];
        gates[(g0 + 16) * 33 + 16 + lq * 4 + r]  = aH1[r];
      }
      if (wid == 0) {
        #pragma unroll
        for (int r = 0; r < 4; ++r) {
          gates[(256 + lr) * 33 + lq * 4 + r]      = aL2[r];
          gates[(256 + lr) * 33 + 16 + lq * 4 + r] = aH2[r];
        }
      }
    }
    __syncthreads();

    // ---- elementwise cell update, 5 pair slots ----
    #pragma unroll
    for (int q = 0; q < 5; ++q) {
      if (q < 4 || tid < 128) {
        const int b = pb_[q], j = pj_[q];
        const int gq = j * 33 + b;
        const float gi = gates[gq];
        const float gf = gates[gq + 2244];    // (68+j)*33+b
        const float gg = gates[gq + 4488];
        const float go = gates[gq + 6732];
        const float ii = sigm(gi), ff = sigm(gf), g2 = tanh_s(gg), oo = sigm(go);
        const float cc = ff * cst[q] + ii * g2;
        cst[q] = cc;
        const float h = oo * tanh_s(cc);
        const _Float16 h16 = (_Float16)h;
        A[b * AW + HOFF + j] = h16;
        if constexpr (LAYER == 0) {
          h0w[t * 4352 + d * 2176 + b * 68 + j] = h16;
        } else {
          const int fo = t * 136 + d * 68 + j;
          #pragma unroll
          for (int k = 0; k < 5; ++k) yk[q][k] += h * fcw[k * 6528 + fo];
        }
      }
    }
    // ---- staging writes for next step ----
    if (st < TT - 1) {
      if constexpr (LAYER == 0) {
        A[sao0] = (_Float16)xp0;
        A[sao1] = (_Float16)xp1;
        if (tid < 64) A[sao2] = (_Float16)xp2;
      } else {
        *(uint2*)&A[sao0] = hp0;
        *(uint2*)&A[sao1] = hp1;
        if (tid < 64) *(uint2*)&A[sao2] = hp2;
      }
    }
    __syncthreads();
  }
}

__global__ __attribute__((amdgpu_flat_work_group_size(NTHR, NTHR)))
void lstm_fc_kernel(
    const float* __restrict__ x,
    const float* __restrict__ Wih0f, const float* __restrict__ Whh0f,
    const float* __restrict__ bih0f, const float* __restrict__ bhh0f,
    const float* __restrict__ Wih0b, const float* __restrict__ Whh0b,
    const float* __restrict__ bih0b, const float* __restrict__ bhh0b,
    const float* __restrict__ Wih1f, const float* __restrict__ Whh1f,
    const float* __restrict__ bih1f, const float* __restrict__ bhh1f,
    const float* __restrict__ Wih1b, const float* __restrict__ Whh1b,
    const float* __restrict__ bih1b, const float* __restrict__ bhh1b,
    const float* __restrict__ fcw, const float* __restrict__ fcb,
    float* __restrict__ out, _Float16* __restrict__ ws)
{
  __shared__ Smem s;
  const int tid = threadIdx.x;
  _Float16* h0w = ws + (size_t)blockIdx.x * H0_SLICE;

  for (int grp = blockIdx.x; grp < NGRP; grp += gridDim.x) {
    const float* xg = x + (size_t)grp * (BT * TT * 34);
    float yk[5][5];
    #pragma unroll
    for (int q = 0; q < 5; ++q)
      #pragma unroll
      for (int k = 0; k < 5; ++k) yk[q][k] = 0.f;

    pass_lstm<0>(s, 0, Wih0f, Whh0f, bih0f, bhh0f, xg, nullptr, h0w, yk);
    pass_lstm<0>(s, 1, Wih0b, Whh0b, bih0b, bhh0b, xg, nullptr, h0w, yk);
    pass_lstm<1>(s, 0, Wih1f, Whh1f, bih1f, bhh1f, nullptr, fcw, h0w, yk);
    pass_lstm<1>(s, 1, Wih1b, Whh1b, bih1b, bhh1b, nullptr, fcw, h0w, yk);

    // ---- FC epilogue: dump pair partials into ysc (overlays gates+A), reduce ----
    #pragma unroll
    for (int q = 0; q < 5; ++q) {
      if (q < 4 || tid < 128) {
        const int p = (q < 4) ? (q * 512 + tid) : (2048 + (tid & 127));
        #pragma unroll
        for (int k = 0; k < 5; ++k) s.u.ysc[p * 5 + k] = yk[q][k];
      }
    }
    __syncthreads();
    if (tid < BT * 5) {
      const int b = tid / 5, k = tid - (tid / 5) * 5;
      float v = fcb[k];
      #pragma unroll 4
      for (int jj = 0; jj < 68; ++jj) v += s.u.ysc[(b * 68 + jj) * 5 + k];
      out[(size_t)(grp * BT + b) * 5 + k] = v;
    }
    __syncthreads();
  }
}

extern "C" void kernel_launch(void* const* d_in, const int* in_sizes, int n_in,
                              void* d_out, int out_size, void* d_ws, size_t ws_size,
                              hipStream_t stream) {
  (void)in_sizes; (void)n_in; (void)out_size;
  static_assert(sizeof(Smem) <= 60 * 1024, "LDS budget");

  const float* x     = (const float*)d_in[0];
  const float* Wih0f = (const float*)d_in[1];
  const float* Whh0f = (const float*)d_in[2];
  const float* bih0f = (const float*)d_in[3];
  const float* bhh0f = (const float*)d_in[4];
  const float* Wih0b = (const float*)d_in[5];
  const float* Whh0b = (const float*)d_in[6];
  const float* bih0b = (const float*)d_in[7];
  const float* bhh0b = (const float*)d_in[8];
  const float* Wih1f = (const float*)d_in[9];
  const float* Whh1f = (const float*)d_in[10];
  const float* bih1f = (const float*)d_in[11];
  const float* bhh1f = (const float*)d_in[12];
  const float* Wih1b = (const float*)d_in[13];
  const float* Whh1b = (const float*)d_in[14];
  const float* bih1b = (const float*)d_in[15];
  const float* bhh1b = (const float*)d_in[16];
  const float* fcw   = (const float*)d_in[17];
  const float* fcb   = (const float*)d_in[18];
  float* out = (float*)d_out;

  int slices = (int)(ws_size / (size_t)(H0_SLICE * 2));
  int grid = slices < 1 ? 1 : (slices > MAXGRID ? MAXGRID : slices);
  if (grid > NGRP) grid = NGRP;

  lstm_fc_kernel<<<dim3(grid), dim3(NTHR), 0, stream>>>(x,
      Wih0f, Whh0f, bih0f, bhh0f, Wih0b, Whh0b, bih0b, bhh0b,
      Wih1f, Whh1f, bih1f, bhh1f, Wih1b, Whh1b, bih1b, bhh1b,
      fcw, fcb, out, (_Float16*)d_ws);
}

// Round 15
// 937.428 us; speedup vs baseline: 1.3458x; 1.3044x over previous
//
#include <hip/hip_runtime.h>

typedef _Float16 half8 __attribute__((ext_vector_type(8)));
typedef float f32x4 __attribute__((ext_vector_type(4)));

#define TT 48
#define BT 32
#define NSEQ 16384
#define NGRP (NSEQ / BT)           // 512 groups
#define NTHR 512
#define MAXGRID 512
#define H0_SLICE (TT * BT * 136)   // f16 elems per block ws slice (417792 B)

// h0w layout: [t][d][b][j], stride per t = 4352 f16
struct __align__(16) Smem {
  float gates[272 * 33];        // 35904 B  [gate][batch(+pad)]
  _Float16 A[32 * 232];         // 14848 B  A panel (L0 view: [32][136])
  union {
    _Float16 bx[7 * 64 * 8];    //  7168 B  LDS B-fragments for tile 16 (during passes)
    float ysc[160];             //  FC combine scratch (after passes)
  } u;
};                              // 57920 B static LDS -> 2 blocks/CU at 128 VGPR

__device__ __forceinline__ float fast_rcp(float v) { return __builtin_amdgcn_rcpf(v); }
__device__ __forceinline__ float sigm(float v)  { return fast_rcp(1.f + __expf(-v)); }
__device__ __forceinline__ float tanh_s(float v){ return 1.f - 2.f * fast_rcp(1.f + __expf(2.f * v)); }

// One (layer, dir) recurrence over 32 sequences, all 8 waves.
// Wave w owns reg B-tiles {2w, 2w+1}; tile 16 via LDS bx (wave 0). M=32 = lo/hi A-tiles.
// Elementwise: thread owns b = tid>>4, j = (tid&15)+16q (+ j=64+(tid&15) if (tid&15)<4).
template <int LAYER>
__device__ __forceinline__ void pass_lstm(Smem& s, const int d,
    const float* __restrict__ Wih, const float* __restrict__ Whh,
    const float* __restrict__ bih, const float* __restrict__ bhh,
    const float* __restrict__ xg,  const float* __restrict__ fcw,
    _Float16* __restrict__ h0w, float (&yk)[5])
{
  constexpr int AW    = LAYER ? 232 : 136;  // A row stride (f16)
  constexpr int KS    = LAYER ? 7 : 4;      // K chunks of 32 (224 / 128)
  constexpr int INW   = LAYER ? 136 : 34;   // non-recurrent width
  constexpr int BIASC = INW + 68;           // bias-one column (204 / 102)
  constexpr int HOFF  = LAYER ? 136 : 34;   // h slot base in A row

  const int tid = threadIdx.x;
  const int ln = tid & 63, wid = tid >> 6;
  const int lr = ln & 15, lq = ln >> 4;

  float* gates = s.gates;
  _Float16* A  = s.A;

  // ---- reg B fragments: 2 tiles per wave ----
  half8 Bf[2][KS];
  #pragma unroll
  for (int i = 0; i < 2; ++i) {
    const int g = (wid * 2 + i) * 16 + lr;
    #pragma unroll
    for (int kk = 0; kk < KS; ++kk) {
      half8 v;
      #pragma unroll
      for (int j = 0; j < 8; ++j) {
        const int k = kk * 32 + lq * 8 + j;
        float wv = 0.f;
        if (k < INW) wv = Wih[g * INW + k];
        else if (k < BIASC) wv = Whh[g * 68 + (k - INW)];
        else if (k == BIASC) wv = bih[g] + bhh[g];
        v[j] = (_Float16)wv;
      }
      Bf[i][kk] = v;
    }
  }
  // ---- LDS B fragments for tile 16 ----
  if (tid < KS * 64) {
    const int kk = tid >> 6, l2 = tid & 63;
    const int g = 256 + (l2 & 15);
    half8 v;
    #pragma unroll
    for (int j = 0; j < 8; ++j) {
      const int k = kk * 32 + (l2 >> 4) * 8 + j;
      float wv = 0.f;
      if (k < INW) wv = Wih[g * INW + k];
      else if (k < BIASC) wv = Whh[g * 68 + (k - INW)];
      else if (k == BIASC) wv = bih[g] + bhh[g];
      v[j] = (_Float16)wv;
    }
    *(half8*)&s.u.bx[tid * 8] = v;
  }

  float cst[5];
  #pragma unroll
  for (int q = 0; q < 5; ++q) cst[q] = 0.f;

  // ---- staging offsets (t-independent); 1088 tasks = 2*512 + 64 extras ----
  int sgo0, sao0, sgo1, sao1, sgo2, sao2;
  if constexpr (LAYER == 0) {
    { const int b = tid / 34, i = tid % 34;
      sgo0 = b * (TT * 34) + i;  sao0 = b * 136 + i; }
    { const int t1 = tid + 512, b = t1 / 34, i = t1 % 34;
      sgo1 = b * (TT * 34) + i;  sao1 = b * 136 + i; }
    { const int t2 = (tid < 64) ? (tid + 1024) : 1024, b = t2 / 34, i = t2 % 34;
      sgo2 = b * (TT * 34) + i;  sao2 = b * 136 + i; }
  } else {
    { const int dd = tid / 544, r = tid % 544, b = r / 17, c = r % 17;
      sgo0 = dd * 2176 + b * 68 + c * 4;  sao0 = b * 232 + dd * 68 + c * 4; }
    { const int t1 = tid + 512, dd = t1 / 544, r = t1 % 544, b = r / 17, c = r % 17;
      sgo1 = dd * 2176 + b * 68 + c * 4;  sao1 = b * 232 + dd * 68 + c * 4; }
    { const int t2 = (tid < 64) ? (tid + 1024) : 1024, dd = t2 / 544, r = t2 % 544,
        b = r / 17, c = r % 17;
      sgo2 = dd * 2176 + b * 68 + c * 4;  sao2 = b * 232 + dd * 68 + c * 4; }
  }

  // ---- prologue: zero A (928 uint4), bias col, stage step 0 ----
  {
    const uint4 zz = {0, 0, 0, 0};
    ((uint4*)A)[tid] = zz;
    if (tid < 416) ((uint4*)A)[512 + tid] = zz;
  }
  __syncthreads();
  if (tid < 32) A[tid * AW + BIASC] = (_Float16)1.f;
  const int t0 = d ? (TT - 1) : 0;
  if constexpr (LAYER == 0) {
    A[sao0] = (_Float16)xg[sgo0 + t0 * 34];
    A[sao1] = (_Float16)xg[sgo1 + t0 * 34];
    if (tid < 64) A[sao2] = (_Float16)xg[sgo2 + t0 * 34];
  } else {
    *(uint2*)&A[sao0] = *(const uint2*)&h0w[sgo0 + t0 * 4352];
    *(uint2*)&A[sao1] = *(const uint2*)&h0w[sgo1 + t0 * 4352];
    if (tid < 64) *(uint2*)&A[sao2] = *(const uint2*)&h0w[sgo2 + t0 * 4352];
  }
  __syncthreads();

  #pragma unroll 1
  for (int st = 0; st < TT; ++st) {
    const int t  = d ? (TT - 1 - st) : st;
    const int tn = d ? (t - 1) : (t + 1);

    // ---- prefetch next step's staging into registers ----
    float xp0 = 0.f, xp1 = 0.f, xp2 = 0.f;
    uint2 hp0 = {0, 0}, hp1 = {0, 0}, hp2 = {0, 0};
    if (st < TT - 1) {
      if constexpr (LAYER == 0) {
        xp0 = xg[sgo0 + tn * 34];
        xp1 = xg[sgo1 + tn * 34];
        if (tid < 64) xp2 = xg[sgo2 + tn * 34];
      } else {
        hp0 = *(const uint2*)&h0w[sgo0 + tn * 4352];
        hp1 = *(const uint2*)&h0w[sgo1 + tn * 4352];
        if (tid < 64) hp2 = *(const uint2*)&h0w[sgo2 + tn * 4352];
      }
    }

    // ---- MFMA: gates(32x272) = A(32xK) . B(Kx272); lo/hi 16-row tiles ----
    f32x4 aL0 = {0.f,0.f,0.f,0.f}, aH0 = {0.f,0.f,0.f,0.f};
    f32x4 aL1 = {0.f,0.f,0.f,0.f}, aH1 = {0.f,0.f,0.f,0.f};
    f32x4 aL2 = {0.f,0.f,0.f,0.f}, aH2 = {0.f,0.f,0.f,0.f};
    #pragma unroll
    for (int kk = 0; kk < KS; ++kk) {
      const half8 alo = *(const half8*)&A[lr * AW + kk * 32 + lq * 8];
      const half8 ahi = *(const half8*)&A[(lr + 16) * AW + kk * 32 + lq * 8];
      aL0 = __builtin_amdgcn_mfma_f32_16x16x32_f16(alo, Bf[0][kk], aL0, 0, 0, 0);
      aH0 = __builtin_amdgcn_mfma_f32_16x16x32_f16(ahi, Bf[0][kk], aH0, 0, 0, 0);
      aL1 = __builtin_amdgcn_mfma_f32_16x16x32_f16(alo, Bf[1][kk], aL1, 0, 0, 0);
      aH1 = __builtin_amdgcn_mfma_f32_16x16x32_f16(ahi, Bf[1][kk], aH1, 0, 0, 0);
      if (wid == 0) {
        const half8 bb = *(const half8*)&s.u.bx[(kk * 64 + ln) * 8];
        aL2 = __builtin_amdgcn_mfma_f32_16x16x32_f16(alo, bb, aL2, 0, 0, 0);
        aH2 = __builtin_amdgcn_mfma_f32_16x16x32_f16(ahi, bb, aH2, 0, 0, 0);
      }
    }
    // C/D: col = lr (gate within tile), row = lq*4+r (batch; +16 for hi tile)
    {
      const int g0 = (wid * 2) * 16 + lr;
      #pragma unroll
      for (int r = 0; r < 4; ++r) {
        gates[g0 * 33 + lq * 4 + r]              = aL0[r];
        gates[g0 * 33 + 16 + lq * 4 + r]         = aH0[r];
        gates[(g0 + 16) * 33 + lq * 4 + r]       = aL1[r];
        gates[(g0 + 16) * 33 + 16 + lq * 4 + r]  = aH1[r];
      }
      if (wid == 0) {
        #pragma unroll
        for (int r = 0; r < 4; ++r) {
          gates[(256 + lr) * 33 + lq * 4 + r]      = aL2[r];
          gates[(256 + lr) * 33 + 16 + lq * 4 + r] = aH2[r];
        }
      }
    }
    __syncthreads();

    // ---- elementwise cell update: b-uniform ownership ----
    {
      const int b = tid >> 4, jb = tid & 15;
      #pragma unroll
      for (int q = 0; q < 5; ++q) {
        if (q < 4 || jb < 4) {
          const int j = (q < 4) ? (jb + 16 * q) : (64 + jb);
          const int gq = j * 33 + b;
          const float gi = gates[gq];
          const float gf = gates[gq + 2244];    // (68+j)*33+b
          const float gg = gates[gq + 4488];
          const float go = gates[gq + 6732];
          const float ii = sigm(gi), ff = sigm(gf), g2 = tanh_s(gg), oo = sigm(go);
          const float cc = ff * cst[q] + ii * g2;
          cst[q] = cc;
          const float h = oo * tanh_s(cc);
          const _Float16 h16 = (_Float16)h;
          A[b * AW + HOFF + j] = h16;
          if constexpr (LAYER == 0) {
            h0w[t * 4352 + d * 2176 + b * 68 + j] = h16;
          } else {
            const int fo = t * 136 + d * 68 + j;
            #pragma unroll
            for (int k = 0; k < 5; ++k) yk[k] += h * fcw[k * 6528 + fo];
          }
        }
      }
    }
    // ---- staging writes for next step ----
    if (st < TT - 1) {
      if constexpr (LAYER == 0) {
        A[sao0] = (_Float16)xp0;
        A[sao1] = (_Float16)xp1;
        if (tid < 64) A[sao2] = (_Float16)xp2;
      } else {
        *(uint2*)&A[sao0] = hp0;
        *(uint2*)&A[sao1] = hp1;
        if (tid < 64) *(uint2*)&A[sao2] = hp2;
      }
    }
    __syncthreads();
  }
}

__global__ __attribute__((amdgpu_flat_work_group_size(NTHR, NTHR)))
void lstm_fc_kernel(
    const float* __restrict__ x,
    const float* __restrict__ Wih0f, const float* __restrict__ Whh0f,
    const float* __restrict__ bih0f, const float* __restrict__ bhh0f,
    const float* __restrict__ Wih0b, const float* __restrict__ Whh0b,
    const float* __restrict__ bih0b, const float* __restrict__ bhh0b,
    const float* __restrict__ Wih1f, const float* __restrict__ Whh1f,
    const float* __restrict__ bih1f, const float* __restrict__ bhh1f,
    const float* __restrict__ Wih1b, const float* __restrict__ Whh1b,
    const float* __restrict__ bih1b, const float* __restrict__ bhh1b,
    const float* __restrict__ fcw, const float* __restrict__ fcb,
    float* __restrict__ out, _Float16* __restrict__ ws)
{
  __shared__ Smem s;
  const int tid = threadIdx.x;
  _Float16* h0w = ws + (size_t)blockIdx.x * H0_SLICE;

  for (int grp = blockIdx.x; grp < NGRP; grp += gridDim.x) {
    const float* xg = x + (size_t)grp * (BT * TT * 34);
    float yk[5] = {0.f, 0.f, 0.f, 0.f, 0.f};

    pass_lstm<0>(s, 0, Wih0f, Whh0f, bih0f, bhh0f, xg, nullptr, h0w, yk);
    pass_lstm<0>(s, 1, Wih0b, Whh0b, bih0b, bhh0b, xg, nullptr, h0w, yk);
    pass_lstm<1>(s, 0, Wih1f, Whh1f, bih1f, bhh1f, nullptr, fcw, h0w, yk);
    pass_lstm<1>(s, 1, Wih1b, Whh1b, bih1b, bhh1b, nullptr, fcw, h0w, yk);

    // ---- FC epilogue: butterfly over the 16 threads sharing b, then combine ----
    #pragma unroll
    for (int m = 1; m < 16; m <<= 1) {
      #pragma unroll
      for (int k = 0; k < 5; ++k) yk[k] += __shfl_xor(yk[k], m, 64);
    }
    __syncthreads();   // all passes done before overwriting bx-union with ysc
    if ((tid & 15) == 0) {
      #pragma unroll
      for (int k = 0; k < 5; ++k) s.u.ysc[(tid >> 4) * 5 + k] = yk[k];
    }
    __syncthreads();
    if (tid < BT * 5) {
      const int k = tid % 5;
      out[(size_t)(grp * BT) * 5 + tid] = s.u.ysc[tid] + fcb[k];
    }
    __syncthreads();
  }
}

extern "C" void kernel_launch(void* const* d_in, const int* in_sizes, int n_in,
                              void* d_out, int out_size, void* d_ws, size_t ws_size,
                              hipStream_t stream) {
  (void)in_sizes; (void)n_in; (void)out_size;
  static_assert(sizeof(Smem) <= 60 * 1024, "LDS budget for 2 blocks/CU");

  const float* x     = (const float*)d_in[0];
  const float* Wih0f = (const float*)d_in[1];
  const float* Whh0f = (const float*)d_in[2];
  const float* bih0f = (const float*)d_in[3];
  const float* bhh0f = (const float*)d_in[4];
  const float* Wih0b = (const float*)d_in[5];
  const float* Whh0b = (const float*)d_in[6];
  const float* bih0b = (const float*)d_in[7];
  const float* bhh0b = (const float*)d_in[8];
  const float* Wih1f = (const float*)d_in[9];
  const float* Whh1f = (const float*)d_in[10];
  const float* bih1f = (const float*)d_in[11];
  const float* bhh1f = (const float*)d_in[12];
  const float* Wih1b = (const float*)d_in[13];
  const float* Whh1b = (const float*)d_in[14];
  const float* bih1b = (const float*)d_in[15];
  const float* bhh1b = (const float*)d_in[16];
  const float* fcw   = (const float*)d_in[17];
  const float* fcb   = (const float*)d_in[18];
  float* out = (float*)d_out;

  int slices = (int)(ws_size / (size_t)(H0_SLICE * 2));
  int grid = slices < 1 ? 1 : (slices > MAXGRID ? MAXGRID : slices);
  if (grid > NGRP) grid = NGRP;

  lstm_fc_kernel<<<dim3(grid), dim3(NTHR), 0, stream>>>(x,
      Wih0f, Whh0f, bih0f, bhh0f, Wih0b, Whh0b, bih0b, bhh0b,
      Wih1f, Whh1f, bih1f, bhh1f, Wih1b, Whh1b, bih1b, bhh1b,
      fcw, fcb, out, (_Float16*)d_ws);
}